// Round 5
// baseline (139.517 us; speedup 1.0000x reference)
//
#include <hip/hip_runtime.h>
#include <hip/hip_cooperative_groups.h>
#include <stdint.h>

namespace cg = cooperative_groups;

// TrajectoryFK: L=65536 timesteps, J=22 joints, 6D-rotation inputs (fp32).
// Output: (L, 22, 3) fp32 joint positions.
// Serial dependency = affine scan (R,p) <- (R @ d_t, p + R @ (d_t v_t));
// element T_t = (d_t, d_t v_t); compose(P,T) = (P.A T.A, P.b + P.A T.b).
// R5: fuse the 3-phase scan into ONE cooperative kernel. R4 spent 99 us on
// 3 launches + a 3MB loc roundtrip; byte-roofline is ~52 MB ≈ 8.5 us.
// Block prefix stays in registers across grid.sync(); every block then
// redundantly scans the 256 block aggregates (parallel, ~1 us) instead of
// paying a second grid sync.

#define LTOT 65536
#define ROW 132                 // 22 joints * 6 floats per timestep (528 B)
#define P1B 256                 // timesteps per block
#define NBLK (LTOT / P1B)       // 256 blocks, 1 per CU

struct Aff { float A[9]; float b[3]; };

__device__ __forceinline__ void d6_to_mat(float a0, float a1, float a2,
                                          float a3, float a4, float a5,
                                          float R[9]) {
  // Gram-Schmidt; columns of R are b1,b2,b3 (row-major R[r*3+c]).
  float n1 = sqrtf(a0 * a0 + a1 * a1 + a2 * a2);
  float i1 = 1.0f / fmaxf(n1, 1e-12f);
  float b10 = a0 * i1, b11 = a1 * i1, b12 = a2 * i1;
  float d = b10 * a3 + b11 * a4 + b12 * a5;
  float c0 = a3 - d * b10, c1 = a4 - d * b11, c2 = a5 - d * b12;
  float n2 = sqrtf(c0 * c0 + c1 * c1 + c2 * c2);
  float i2 = 1.0f / fmaxf(n2, 1e-12f);
  float b20 = c0 * i2, b21 = c1 * i2, b22 = c2 * i2;
  float b30 = b11 * b22 - b12 * b21;
  float b31 = b12 * b20 - b10 * b22;
  float b32 = b10 * b21 - b11 * b20;
  R[0] = b10; R[1] = b20; R[2] = b30;
  R[3] = b11; R[4] = b21; R[5] = b31;
  R[6] = b12; R[7] = b22; R[8] = b32;
}

__device__ __forceinline__ void mat_mul(const float A[9], const float B[9], float C[9]) {
#pragma unroll
  for (int i = 0; i < 3; ++i)
#pragma unroll
    for (int j = 0; j < 3; ++j)
      C[i * 3 + j] = A[i * 3 + 0] * B[0 + j] + A[i * 3 + 1] * B[3 + j] + A[i * 3 + 2] * B[6 + j];
}

__device__ __forceinline__ void mat_vec(const float A[9], float x, float y, float z,
                                        float& ox, float& oy, float& oz) {
  ox = A[0] * x + A[1] * y + A[2] * z;
  oy = A[3] * x + A[4] * y + A[5] * z;
  oz = A[6] * x + A[7] * y + A[8] * z;
}

__device__ __forceinline__ void compose(const Aff& P, const Aff& T, Aff& O) {
  mat_mul(P.A, T.A, O.A);
  float bx, by, bz;
  mat_vec(P.A, T.b[0], T.b[1], T.b[2], bx, by, bz);
  O.b[0] = P.b[0] + bx; O.b[1] = P.b[1] + by; O.b[2] = P.b[2] + bz;
}

__device__ __forceinline__ void aff_identity(Aff& v) {
  v.A[0] = 1.f; v.A[1] = 0.f; v.A[2] = 0.f;
  v.A[3] = 0.f; v.A[4] = 1.f; v.A[5] = 0.f;
  v.A[6] = 0.f; v.A[7] = 0.f; v.A[8] = 1.f;
  v.b[0] = 0.f; v.b[1] = 0.f; v.b[2] = 0.f;
}

// Inclusive Hillis-Steele scan across the 64-lane wave.
__device__ __forceinline__ void wave_scan(Aff& v, int lane) {
#pragma unroll
  for (int s = 1; s < 64; s <<= 1) {
    Aff u;
#pragma unroll
    for (int k = 0; k < 9; ++k) u.A[k] = __shfl_up(v.A[k], s, 64);
#pragma unroll
    for (int k = 0; k < 3; ++k) u.b[k] = __shfl_up(v.b[k], s, 64);
    if (lane >= s) { Aff t; compose(u, v, t); v = t; }
  }
}

// Block-local scan: wave scan + cross-wave LDS compose. Returns inclusive
// block-local prefix in f; v must hold the lane's element on entry.
__device__ __forceinline__ void block_scan(Aff& v, int lane, int wid,
                                           float (*sagg)[12], Aff& f) {
  wave_scan(v, lane);
  if (lane == 63) {
#pragma unroll
    for (int k = 0; k < 9; ++k) sagg[wid][k] = v.A[k];
#pragma unroll
    for (int k = 0; k < 3; ++k) sagg[wid][9 + k] = v.b[k];
  }
  __syncthreads();
  Aff pre; aff_identity(pre);
  for (int w = 0; w < wid; ++w) {   // <=3 compositions, broadcast LDS reads
    Aff g, t2;
#pragma unroll
    for (int k = 0; k < 9; ++k) g.A[k] = sagg[w][k];
#pragma unroll
    for (int k = 0; k < 3; ++k) g.b[k] = sagg[w][9 + k];
    compose(pre, g, t2); pre = t2;
  }
  compose(pre, v, f);
}

__global__ __launch_bounds__(P1B, 1) void fk_fused(const float* __restrict__ pred,
                                                   const float* __restrict__ offs,
                                                   float* __restrict__ agg,
                                                   float* __restrict__ out) {
  cg::grid_group grid = cg::this_grid();
  int tid = threadIdx.x;
  int t = blockIdx.x * P1B + tid;
  int lane = tid & 63, wid = tid >> 6;

  __shared__ float sagg1[P1B / 64][12];
  __shared__ float sagg2[P1B / 64][12];
  __shared__ float sincl[NBLK][13];        // +1 pad: write stride 13 kills conflicts

  // ---- element transform (all sqrt/div parallel across 65536 lanes) ----
  const float4* q4 = (const float4*)(pred + (size_t)t * ROW);  // 16B-aligned
  float4 qa = q4[0];   // j0: v0 v1 v2 .
  float4 qb = q4[1];   // . . e0 e1
  float4 qc = q4[2];   // e2 e3 e4 e5
  Aff v;
  d6_to_mat(qb.z, qb.w, qc.x, qc.y, qc.z, qc.w, v.A);          // d_t
  mat_vec(v.A, qa.x, qa.y, qa.z, v.b[0], v.b[1], v.b[2]);      // d_t @ v_t

  // ---- block-local scan; f stays in registers across grid.sync() ----
  Aff f;
  block_scan(v, lane, wid, sagg1, f);

  if (tid == P1B - 1) {
    float4* a = (float4*)(agg + (size_t)blockIdx.x * 12);
    a[0] = make_float4(f.A[0], f.A[1], f.A[2], f.A[3]);
    a[1] = make_float4(f.A[4], f.A[5], f.A[6], f.A[7]);
    a[2] = make_float4(f.A[8], f.b[0], f.b[1], f.b[2]);
  }
  __threadfence();            // device-scope release of agg
  grid.sync();

  // ---- redundant per-block scan of the 256 block aggregates ----
  Aff v2;
  {
    const float4* a = (const float4*)(agg + (size_t)tid * 12);
    float4 a0 = a[0], a1 = a[1], a2 = a[2];
    v2.A[0] = a0.x; v2.A[1] = a0.y; v2.A[2] = a0.z; v2.A[3] = a0.w;
    v2.A[4] = a1.x; v2.A[5] = a1.y; v2.A[6] = a1.z; v2.A[7] = a1.w;
    v2.A[8] = a2.x; v2.b[0] = a2.y; v2.b[1] = a2.z; v2.b[2] = a2.w;
  }
  Aff incl;
  block_scan(v2, lane, wid, sagg2, incl);
#pragma unroll
  for (int k = 0; k < 9; ++k) sincl[tid][k] = incl.A[k];
#pragma unroll
  for (int k = 0; k < 3; ++k) sincl[tid][9 + k] = incl.b[k];
  __syncthreads();

  Aff eb;                     // exclusive prefix for THIS block
  if (blockIdx.x == 0) {
    aff_identity(eb);
  } else {
    const float* sp = sincl[blockIdx.x - 1];   // broadcast read
#pragma unroll
    for (int k = 0; k < 9; ++k) eb.A[k] = sp[k];
#pragma unroll
    for (int k = 0; k < 3; ++k) eb.b[k] = sp[9 + k];
  }

  Aff g;                      // global prefix for timestep t
  compose(eb, f, g);
  const float* R = g.A;       // global R[t]
  float ov[66];
  ov[0] = g.b[0]; ov[1] = g.b[1]; ov[2] = g.b[2];   // root_pos

  // ---- joint tree ----
  const float* q = pred + (size_t)t * ROW;

#define CHILD(j, p, Rp)                                                        \
  {                                                                            \
    float ox, oy, oz;                                                          \
    mat_vec(Rp, offs[(j)*3 + 0], offs[(j)*3 + 1], offs[(j)*3 + 2], ox, oy, oz);\
    ov[(j)*3 + 0] = ov[(p)*3 + 0] + ox;                                        \
    ov[(j)*3 + 1] = ov[(p)*3 + 1] + oy;                                        \
    ov[(j)*3 + 2] = ov[(p)*3 + 2] + oz;                                        \
  }
#define ROTJ(j, Rp, Rj)                                                        \
  {                                                                            \
    const float2* qq = (const float2*)(q + (j)*6); /* 8B-aligned */            \
    float2 w0 = qq[0], w1 = qq[1], w2 = qq[2];                                 \
    float Mx[9];                                                               \
    d6_to_mat(w0.x, w0.y, w1.x, w1.y, w2.x, w2.y, Mx);                         \
    mat_mul(Rp, Mx, Rj);                                                       \
  }

  CHILD(1, 0, R);
  float r2[9], r3[9], r4[9];
  CHILD(2, 0, R); ROTJ(2, R, r2);
  CHILD(3, 0, R); ROTJ(3, R, r3);
  CHILD(4, 1, R); ROTJ(4, R, r4);
  float r5[9], r6[9], r7[9];
  CHILD(5, 2, r2); ROTJ(5, r2, r5);
  CHILD(6, 3, r3); ROTJ(6, r3, r6);
  CHILD(7, 4, r4); ROTJ(7, r4, r7);
  float r8[9], r9[9];
  CHILD(8, 5, r5); ROTJ(8, r5, r8);
  CHILD(9, 6, r6); ROTJ(9, r6, r9);
  CHILD(10, 7, r7);                 // leaf
  CHILD(11, 8, r8);                 // leaf
  float r12[9], r13[9], r14[9];
  CHILD(12, 9, r9); ROTJ(12, r9, r12);
  CHILD(13, 9, r9); ROTJ(13, r9, r13);
  CHILD(14, 9, r9); ROTJ(14, r9, r14);
  CHILD(15, 12, r12);               // leaf
  float r16[9], r17[9];
  CHILD(16, 13, r13); ROTJ(16, r13, r16);
  CHILD(17, 14, r14); ROTJ(17, r14, r17);
  float r18[9], r19[9];
  CHILD(18, 16, r16); ROTJ(18, r16, r18);
  CHILD(19, 17, r17); ROTJ(19, r17, r19);
  CHILD(20, 18, r18);               // leaf
  CHILD(21, 19, r19);               // leaf

  // Store 66 fp32 per t (264 B row, 8B-aligned) as 33 float2.
  float2* ob = (float2*)(out + (size_t)t * 66);
#pragma unroll
  for (int k = 0; k < 33; ++k) ob[k] = make_float2(ov[2 * k], ov[2 * k + 1]);
#undef CHILD
#undef ROTJ
}

extern "C" void kernel_launch(void* const* d_in, const int* in_sizes, int n_in,
                              void* d_out, int out_size, void* d_ws, size_t ws_size,
                              hipStream_t stream) {
  const float* pred = (const float*)d_in[0];   // (L, 22, 6) fp32
  const float* offs = (const float*)d_in[1];   // (22, 3)    fp32
  float* out = (float*)d_out;                  // (L, 22, 3) fp32
  float* agg = (float*)d_ws;                   // 12 * NBLK floats

  void* args[] = { (void*)&pred, (void*)&offs, (void*)&agg, (void*)&out };
  hipLaunchCooperativeKernel((void*)fk_fused, dim3(NBLK), dim3(P1B),
                             args, 0, stream);
}

// Round 6
// 96.700 us; speedup vs baseline: 1.4428x; 1.4428x over previous
//
#include <hip/hip_runtime.h>
#include <stdint.h>

// TrajectoryFK: L=65536 timesteps, J=22 joints, 6D-rotation inputs (fp32).
// Output: (L, 22, 3) fp32 joint positions.
// Serial dependency = affine scan (R,p) <- (R @ d_t, p + R @ (d_t v_t));
// element T_t = (d_t, d_t v_t); compose(P,T) = (P.A T.A, P.b + P.A T.b).
// R6: two PLAIN launches (cooperative launch cost ~40-80 us overhead in R5).
// K1 writes only 256 block aggregates (48 B each). K2 re-derives the block
// scan in registers (~2 us VALU, cheaper than a 6 MB loc roundtrip), scans
// the aggregates redundantly per block (L2-hot broadcast), then the tree.

#define LTOT 65536
#define ROW 132                 // 22 joints * 6 floats per timestep (528 B)
#define P1B 256                 // timesteps per block
#define NBLK (LTOT / P1B)       // 256 blocks

struct Aff { float A[9]; float b[3]; };

__device__ __forceinline__ void d6_to_mat(float a0, float a1, float a2,
                                          float a3, float a4, float a5,
                                          float R[9]) {
  // Gram-Schmidt; columns of R are b1,b2,b3 (row-major R[r*3+c]).
  float n1 = sqrtf(a0 * a0 + a1 * a1 + a2 * a2);
  float i1 = 1.0f / fmaxf(n1, 1e-12f);
  float b10 = a0 * i1, b11 = a1 * i1, b12 = a2 * i1;
  float d = b10 * a3 + b11 * a4 + b12 * a5;
  float c0 = a3 - d * b10, c1 = a4 - d * b11, c2 = a5 - d * b12;
  float n2 = sqrtf(c0 * c0 + c1 * c1 + c2 * c2);
  float i2 = 1.0f / fmaxf(n2, 1e-12f);
  float b20 = c0 * i2, b21 = c1 * i2, b22 = c2 * i2;
  float b30 = b11 * b22 - b12 * b21;
  float b31 = b12 * b20 - b10 * b22;
  float b32 = b10 * b21 - b11 * b20;
  R[0] = b10; R[1] = b20; R[2] = b30;
  R[3] = b11; R[4] = b21; R[5] = b31;
  R[6] = b12; R[7] = b22; R[8] = b32;
}

__device__ __forceinline__ void mat_mul(const float A[9], const float B[9], float C[9]) {
#pragma unroll
  for (int i = 0; i < 3; ++i)
#pragma unroll
    for (int j = 0; j < 3; ++j)
      C[i * 3 + j] = A[i * 3 + 0] * B[0 + j] + A[i * 3 + 1] * B[3 + j] + A[i * 3 + 2] * B[6 + j];
}

__device__ __forceinline__ void mat_vec(const float A[9], float x, float y, float z,
                                        float& ox, float& oy, float& oz) {
  ox = A[0] * x + A[1] * y + A[2] * z;
  oy = A[3] * x + A[4] * y + A[5] * z;
  oz = A[6] * x + A[7] * y + A[8] * z;
}

__device__ __forceinline__ void compose(const Aff& P, const Aff& T, Aff& O) {
  mat_mul(P.A, T.A, O.A);
  float bx, by, bz;
  mat_vec(P.A, T.b[0], T.b[1], T.b[2], bx, by, bz);
  O.b[0] = P.b[0] + bx; O.b[1] = P.b[1] + by; O.b[2] = P.b[2] + bz;
}

__device__ __forceinline__ void aff_identity(Aff& v) {
  v.A[0] = 1.f; v.A[1] = 0.f; v.A[2] = 0.f;
  v.A[3] = 0.f; v.A[4] = 1.f; v.A[5] = 0.f;
  v.A[6] = 0.f; v.A[7] = 0.f; v.A[8] = 1.f;
  v.b[0] = 0.f; v.b[1] = 0.f; v.b[2] = 0.f;
}

// Inclusive Hillis-Steele scan across the 64-lane wave.
__device__ __forceinline__ void wave_scan(Aff& v, int lane) {
#pragma unroll
  for (int s = 1; s < 64; s <<= 1) {
    Aff u;
#pragma unroll
    for (int k = 0; k < 9; ++k) u.A[k] = __shfl_up(v.A[k], s, 64);
#pragma unroll
    for (int k = 0; k < 3; ++k) u.b[k] = __shfl_up(v.b[k], s, 64);
    if (lane >= s) { Aff t; compose(u, v, t); v = t; }
  }
}

// Block-local scan: wave scan + cross-wave LDS compose -> inclusive prefix f.
__device__ __forceinline__ void block_scan(Aff& v, int lane, int wid,
                                           float (*sagg)[12], Aff& f) {
  wave_scan(v, lane);
  if (lane == 63) {
#pragma unroll
    for (int k = 0; k < 9; ++k) sagg[wid][k] = v.A[k];
#pragma unroll
    for (int k = 0; k < 3; ++k) sagg[wid][9 + k] = v.b[k];
  }
  __syncthreads();
  Aff pre; aff_identity(pre);
  for (int w = 0; w < wid; ++w) {   // <=3 compositions, broadcast LDS reads
    Aff g, t2;
#pragma unroll
    for (int k = 0; k < 9; ++k) g.A[k] = sagg[w][k];
#pragma unroll
    for (int k = 0; k < 3; ++k) g.b[k] = sagg[w][9 + k];
    compose(pre, g, t2); pre = t2;
  }
  compose(pre, v, f);
}

// Element transform for timestep t from the row prefix (48 B).
__device__ __forceinline__ void elem_transform(const float* __restrict__ pred,
                                               int t, Aff& v) {
  const float4* q4 = (const float4*)(pred + (size_t)t * ROW);  // 16B-aligned
  float4 qa = q4[0];   // j0: v0 v1 v2 .
  float4 qb = q4[1];   // . . e0 e1
  float4 qc = q4[2];   // e2 e3 e4 e5
  d6_to_mat(qb.z, qb.w, qc.x, qc.y, qc.z, qc.w, v.A);          // d_t
  mat_vec(v.A, qa.x, qa.y, qa.z, v.b[0], v.b[1], v.b[2]);      // d_t @ v_t
}

// ---------------- K1: block aggregates only ----------------
__global__ __launch_bounds__(P1B) void fk_agg(const float* __restrict__ pred,
                                              float* __restrict__ agg) {
  int tid = threadIdx.x;
  int t = blockIdx.x * P1B + tid;
  int lane = tid & 63, wid = tid >> 6;
  Aff v;
  elem_transform(pred, t, v);
  wave_scan(v, lane);
  __shared__ float sagg[P1B / 64][12];
  if (lane == 63) {
#pragma unroll
    for (int k = 0; k < 9; ++k) sagg[wid][k] = v.A[k];
#pragma unroll
    for (int k = 0; k < 3; ++k) sagg[wid][9 + k] = v.b[k];
  }
  __syncthreads();
  if (tid == P1B - 1) {      // v == inclusive of last wave
    Aff pre; aff_identity(pre);
    for (int w = 0; w < P1B / 64 - 1; ++w) {
      Aff g, t2;
#pragma unroll
      for (int k = 0; k < 9; ++k) g.A[k] = sagg[w][k];
#pragma unroll
      for (int k = 0; k < 3; ++k) g.b[k] = sagg[w][9 + k];
      compose(pre, g, t2); pre = t2;
    }
    Aff f; compose(pre, v, f);
    float4* a = (float4*)(agg + (size_t)blockIdx.x * 12);
    a[0] = make_float4(f.A[0], f.A[1], f.A[2], f.A[3]);
    a[1] = make_float4(f.A[4], f.A[5], f.A[6], f.A[7]);
    a[2] = make_float4(f.A[8], f.b[0], f.b[1], f.b[2]);
  }
}

// ---------------- K2: block scan (re-derived) + agg scan + tree -----------
__global__ __launch_bounds__(P1B) void fk_main(const float* __restrict__ pred,
                                               const float* __restrict__ offs,
                                               const float* __restrict__ agg,
                                               float* __restrict__ out) {
  int tid = threadIdx.x;
  int t = blockIdx.x * P1B + tid;
  int lane = tid & 63, wid = tid >> 6;

  __shared__ float sagg1[P1B / 64][12];
  __shared__ float sagg2[P1B / 64][12];
  __shared__ float sincl[NBLK][13];   // +1 pad kills write bank conflicts

  // Issue the aggregate load early to overlap with the block scan.
  Aff v2;
  {
    const float4* a = (const float4*)(agg + (size_t)tid * 12);
    float4 a0 = a[0], a1 = a[1], a2 = a[2];
    v2.A[0] = a0.x; v2.A[1] = a0.y; v2.A[2] = a0.z; v2.A[3] = a0.w;
    v2.A[4] = a1.x; v2.A[5] = a1.y; v2.A[6] = a1.z; v2.A[7] = a1.w;
    v2.A[8] = a2.x; v2.b[0] = a2.y; v2.b[1] = a2.z; v2.b[2] = a2.w;
  }

  Aff v, f;
  elem_transform(pred, t, v);
  block_scan(v, lane, wid, sagg1, f);      // block-local inclusive prefix

  Aff incl;
  block_scan(v2, lane, wid, sagg2, incl);  // inclusive scan of aggregates
#pragma unroll
  for (int k = 0; k < 9; ++k) sincl[tid][k] = incl.A[k];
#pragma unroll
  for (int k = 0; k < 3; ++k) sincl[tid][9 + k] = incl.b[k];
  __syncthreads();

  Aff eb;                     // exclusive prefix for THIS block
  if (blockIdx.x == 0) {
    aff_identity(eb);
  } else {
    const float* sp = sincl[blockIdx.x - 1];   // broadcast read
#pragma unroll
    for (int k = 0; k < 9; ++k) eb.A[k] = sp[k];
#pragma unroll
    for (int k = 0; k < 3; ++k) eb.b[k] = sp[9 + k];
  }

  Aff g;                      // global prefix for timestep t
  compose(eb, f, g);
  const float* R = g.A;       // global R[t]
  float ov[66];
  ov[0] = g.b[0]; ov[1] = g.b[1]; ov[2] = g.b[2];   // root_pos

  const float* q = pred + (size_t)t * ROW;

#define CHILD(j, p, Rp)                                                        \
  {                                                                            \
    float ox, oy, oz;                                                          \
    mat_vec(Rp, offs[(j)*3 + 0], offs[(j)*3 + 1], offs[(j)*3 + 2], ox, oy, oz);\
    ov[(j)*3 + 0] = ov[(p)*3 + 0] + ox;                                        \
    ov[(j)*3 + 1] = ov[(p)*3 + 1] + oy;                                        \
    ov[(j)*3 + 2] = ov[(p)*3 + 2] + oz;                                        \
  }
#define ROTJ(j, Rp, Rj)                                                        \
  {                                                                            \
    const float2* qq = (const float2*)(q + (j)*6); /* 8B-aligned */            \
    float2 w0 = qq[0], w1 = qq[1], w2 = qq[2];                                 \
    float Mx[9];                                                               \
    d6_to_mat(w0.x, w0.y, w1.x, w1.y, w2.x, w2.y, Mx);                         \
    mat_mul(Rp, Mx, Rj);                                                       \
  }

  CHILD(1, 0, R);
  float r2[9], r3[9], r4[9];
  CHILD(2, 0, R); ROTJ(2, R, r2);
  CHILD(3, 0, R); ROTJ(3, R, r3);
  CHILD(4, 1, R); ROTJ(4, R, r4);
  float r5[9], r6[9], r7[9];
  CHILD(5, 2, r2); ROTJ(5, r2, r5);
  CHILD(6, 3, r3); ROTJ(6, r3, r6);
  CHILD(7, 4, r4); ROTJ(7, r4, r7);
  float r8[9], r9[9];
  CHILD(8, 5, r5); ROTJ(8, r5, r8);
  CHILD(9, 6, r6); ROTJ(9, r6, r9);
  CHILD(10, 7, r7);                 // leaf
  CHILD(11, 8, r8);                 // leaf
  float r12[9], r13[9], r14[9];
  CHILD(12, 9, r9); ROTJ(12, r9, r12);
  CHILD(13, 9, r9); ROTJ(13, r9, r13);
  CHILD(14, 9, r9); ROTJ(14, r9, r14);
  CHILD(15, 12, r12);               // leaf
  float r16[9], r17[9];
  CHILD(16, 13, r13); ROTJ(16, r13, r16);
  CHILD(17, 14, r14); ROTJ(17, r14, r17);
  float r18[9], r19[9];
  CHILD(18, 16, r16); ROTJ(18, r16, r18);
  CHILD(19, 17, r17); ROTJ(19, r17, r19);
  CHILD(20, 18, r18);               // leaf
  CHILD(21, 19, r19);               // leaf

  // Store 66 fp32 per t (264 B row, 8B-aligned) as 33 float2.
  float2* ob = (float2*)(out + (size_t)t * 66);
#pragma unroll
  for (int k = 0; k < 33; ++k) ob[k] = make_float2(ov[2 * k], ov[2 * k + 1]);
#undef CHILD
#undef ROTJ
}

extern "C" void kernel_launch(void* const* d_in, const int* in_sizes, int n_in,
                              void* d_out, int out_size, void* d_ws, size_t ws_size,
                              hipStream_t stream) {
  const float* pred = (const float*)d_in[0];   // (L, 22, 6) fp32
  const float* offs = (const float*)d_in[1];   // (22, 3)    fp32
  float* out = (float*)d_out;                  // (L, 22, 3) fp32
  float* agg = (float*)d_ws;                   // 12 * NBLK floats

  fk_agg<<<NBLK, P1B, 0, stream>>>(pred, agg);
  fk_main<<<NBLK, P1B, 0, stream>>>(pred, offs, agg, out);
}